// Round 1
// baseline (743.277 us; speedup 1.0000x reference)
//
#include <hip/hip_runtime.h>
#include <stdint.h>

// Problem: B=8, C=256, H=128, W=128. out = W[256,1280] @ concat(x,cummaxH,revcummaxH,cummaxW,revcummaxW) + bias
// GEMM: M=256, K=1280, N=131072 in bf16 MFMA, fp32 accumulate.
// ws layout:
//   wsA: [256][1280] bf16 weights (k-contiguous)                       655,360 B
//   wsB: [kb=160][n=131072][j=8] bf16  (k = kb*8+j, k-contiguous 8)  335,544,320 B
// total ws ≈ 320.6 MiB required.

#define HW_ 16384
#define N_  131072
#define K_  1280

typedef unsigned short ushort8v __attribute__((ext_vector_type(8)));
typedef unsigned short ushort4v __attribute__((ext_vector_type(4)));
typedef short          short8v  __attribute__((ext_vector_type(8)));
typedef float          float4v  __attribute__((ext_vector_type(4)));

__device__ __forceinline__ unsigned short f2bf(float f) {
    unsigned int u = __builtin_bit_cast(unsigned int, f);
    u += 0x7fffu + ((u >> 16) & 1u);           // RNE
    return (unsigned short)(u >> 16);
}

__device__ __forceinline__ void load_lds16(const void* g, void* l) {
    __builtin_amdgcn_global_load_lds(
        (const __attribute__((address_space(1))) uint32_t*)g,
        (__attribute__((address_space(3))) uint32_t*)l,
        16, 0, 0);
}

// ---- weights fp32 -> bf16, same [M][K] layout (k-contiguous) ----
__global__ void repack_w(const float* __restrict__ w, unsigned short* __restrict__ wsA) {
    int idx = blockIdx.x * 256 + threadIdx.x;          // 81920 threads, 4 elems each
    float4 v = ((const float4*)w)[idx];
    ushort4v o = { f2bf(v.x), f2bf(v.y), f2bf(v.z), f2bf(v.w) };
    *(ushort4v*)(wsA + (size_t)idx * 4) = o;
}

// ---- v0 (x), v1 (prefix max over h), v2 (suffix max over h) ----
// thread owns (b, cb, w, half): 4 channels c = cb*8 + half*4 + j. 65536 threads.
__global__ void scan_h(const float* __restrict__ x, unsigned short* __restrict__ wsB) {
    int idx  = blockIdx.x * 256 + threadIdx.x;
    int half = idx & 1;
    int w    = (idx >> 1) & 127;
    int cb   = (idx >> 8) & 31;
    int b    = idx >> 13;
    const float* src = x + (((size_t)(b * 256 + cb * 8 + half * 4)) << 14) + w;
    size_t nbase = ((size_t)b << 14) + w;
    unsigned short* d0 = wsB + (((size_t)(cb)      * N_ + nbase) << 3) + half * 4;
    unsigned short* d1 = wsB + (((size_t)(32 + cb) * N_ + nbase) << 3) + half * 4;
    unsigned short* d2 = wsB + (((size_t)(64 + cb) * N_ + nbase) << 3) + half * 4;

    float r0 = -INFINITY, r1 = -INFINITY, r2 = -INFINITY, r3 = -INFINITY;
    for (int h = 0; h < 128; h += 2) {
        float a0 = src[(0 << 14) + (h << 7)], a1 = src[(1 << 14) + (h << 7)];
        float a2 = src[(2 << 14) + (h << 7)], a3 = src[(3 << 14) + (h << 7)];
        float b0 = src[(0 << 14) + ((h + 1) << 7)], b1 = src[(1 << 14) + ((h + 1) << 7)];
        float b2 = src[(2 << 14) + ((h + 1) << 7)], b3 = src[(3 << 14) + ((h + 1) << 7)];
        ushort4v xo0 = { f2bf(a0), f2bf(a1), f2bf(a2), f2bf(a3) };
        *(ushort4v*)(d0 + ((size_t)h << 10)) = xo0;
        r0 = fmaxf(r0, a0); r1 = fmaxf(r1, a1); r2 = fmaxf(r2, a2); r3 = fmaxf(r3, a3);
        ushort4v p0 = { f2bf(r0), f2bf(r1), f2bf(r2), f2bf(r3) };
        *(ushort4v*)(d1 + ((size_t)h << 10)) = p0;
        ushort4v xo1 = { f2bf(b0), f2bf(b1), f2bf(b2), f2bf(b3) };
        *(ushort4v*)(d0 + ((size_t)(h + 1) << 10)) = xo1;
        r0 = fmaxf(r0, b0); r1 = fmaxf(r1, b1); r2 = fmaxf(r2, b2); r3 = fmaxf(r3, b3);
        ushort4v p1 = { f2bf(r0), f2bf(r1), f2bf(r2), f2bf(r3) };
        *(ushort4v*)(d1 + ((size_t)(h + 1) << 10)) = p1;
    }
    // suffix pass
    r0 = r1 = r2 = r3 = -INFINITY;
    for (int h = 127; h > 0; h -= 2) {
        float a0 = src[(0 << 14) + (h << 7)], a1 = src[(1 << 14) + (h << 7)];
        float a2 = src[(2 << 14) + (h << 7)], a3 = src[(3 << 14) + (h << 7)];
        float b0 = src[(0 << 14) + ((h - 1) << 7)], b1 = src[(1 << 14) + ((h - 1) << 7)];
        float b2 = src[(2 << 14) + ((h - 1) << 7)], b3 = src[(3 << 14) + ((h - 1) << 7)];
        r0 = fmaxf(r0, a0); r1 = fmaxf(r1, a1); r2 = fmaxf(r2, a2); r3 = fmaxf(r3, a3);
        ushort4v s0 = { f2bf(r0), f2bf(r1), f2bf(r2), f2bf(r3) };
        *(ushort4v*)(d2 + ((size_t)h << 10)) = s0;
        r0 = fmaxf(r0, b0); r1 = fmaxf(r1, b1); r2 = fmaxf(r2, b2); r3 = fmaxf(r3, b3);
        ushort4v s1 = { f2bf(r0), f2bf(r1), f2bf(r2), f2bf(r3) };
        *(ushort4v*)(d2 + ((size_t)(h - 1) << 10)) = s1;
    }
}

// ---- v3 (prefix max over w), v4 (suffix max over w) ----
// thread owns (b, cb, h): 8 channels, streams the row with float4. 32768 threads.
__global__ void scan_w(const float* __restrict__ x, unsigned short* __restrict__ wsB) {
    int idx = blockIdx.x * 256 + threadIdx.x;
    int h  = idx & 127;
    int cb = (idx >> 7) & 31;
    int b  = idx >> 12;
    const float* src = x + (((size_t)(b * 256 + cb * 8)) << 14) + (h << 7);
    size_t nbase = ((size_t)b << 14) + (h << 7);
    unsigned short* d3 = wsB + (((size_t)(96  + cb) * N_ + nbase) << 3);
    unsigned short* d4 = wsB + (((size_t)(128 + cb) * N_ + nbase) << 3);

    float r[8];
#pragma unroll
    for (int j = 0; j < 8; ++j) r[j] = -INFINITY;
    for (int wq = 0; wq < 32; ++wq) {
        float4 v[8];
#pragma unroll
        for (int j = 0; j < 8; ++j) v[j] = *(const float4*)(src + (j << 14) + wq * 4);
        ushort8v o0, o1, o2, o3;
#pragma unroll
        for (int j = 0; j < 8; ++j) {
            float t = r[j];
            t = fmaxf(t, v[j].x); o0[j] = f2bf(t);
            t = fmaxf(t, v[j].y); o1[j] = f2bf(t);
            t = fmaxf(t, v[j].z); o2[j] = f2bf(t);
            t = fmaxf(t, v[j].w); o3[j] = f2bf(t);
            r[j] = t;
        }
        *(ushort8v*)(d3 + ((size_t)(wq * 4 + 0) << 3)) = o0;
        *(ushort8v*)(d3 + ((size_t)(wq * 4 + 1) << 3)) = o1;
        *(ushort8v*)(d3 + ((size_t)(wq * 4 + 2) << 3)) = o2;
        *(ushort8v*)(d3 + ((size_t)(wq * 4 + 3) << 3)) = o3;
    }
#pragma unroll
    for (int j = 0; j < 8; ++j) r[j] = -INFINITY;
    for (int wq = 31; wq >= 0; --wq) {
        float4 v[8];
#pragma unroll
        for (int j = 0; j < 8; ++j) v[j] = *(const float4*)(src + (j << 14) + wq * 4);
        ushort8v o0, o1, o2, o3;
#pragma unroll
        for (int j = 0; j < 8; ++j) {
            float t = r[j];
            t = fmaxf(t, v[j].w); o3[j] = f2bf(t);
            t = fmaxf(t, v[j].z); o2[j] = f2bf(t);
            t = fmaxf(t, v[j].y); o1[j] = f2bf(t);
            t = fmaxf(t, v[j].x); o0[j] = f2bf(t);
            r[j] = t;
        }
        *(ushort8v*)(d4 + ((size_t)(wq * 4 + 0) << 3)) = o0;
        *(ushort8v*)(d4 + ((size_t)(wq * 4 + 1) << 3)) = o1;
        *(ushort8v*)(d4 + ((size_t)(wq * 4 + 2) << 3)) = o2;
        *(ushort8v*)(d4 + ((size_t)(wq * 4 + 3) << 3)) = o3;
    }
}

// ---- GEMM: C[256,131072] = A[256,1280] * B[1280,131072], bf16 MFMA ----
// 128x128 tile, BK=32, 4 waves of 4x4 16x16x32 MFMA. m97-style 2-barrier K-loop.
__global__ __launch_bounds__(256) void gemm_k(
    const unsigned short* __restrict__ wsA, const unsigned short* __restrict__ wsB,
    const float* __restrict__ bias, float* __restrict__ out) {
    __shared__ __align__(16) unsigned short As[128 * 32];      // [m][k] k-contig, 8 KB
    __shared__ __align__(16) unsigned short Bs[4 * 128 * 8];   // [kb][n][j], 8 KB

    int tid  = threadIdx.x;
    int lane = tid & 63, wid = tid >> 6;
    int m0 = blockIdx.y << 7;
    int n0 = blockIdx.x << 7;
    int wy = wid >> 1, wx = wid & 1;
    int q  = lane >> 4, lr = lane & 15;

    float4v acc[4][4];
#pragma unroll
    for (int mi = 0; mi < 4; ++mi)
#pragma unroll
        for (int ni = 0; ni < 4; ++ni)
            acc[mi][ni] = (float4v){0.f, 0.f, 0.f, 0.f};

    for (int kt = 0; kt < 40; ++kt) {
        int k0 = kt << 5;
#pragma unroll
        for (int r = 0; r < 2; ++r) {               // stage A: 512 chunks of 16B
            int ch = (r << 8) + tid;
            const unsigned short* ga = wsA + (size_t)(m0 + (ch >> 2)) * K_ + k0 + ((ch & 3) << 3);
            load_lds16(ga, (char*)As + (r << 12) + (wid << 10));
        }
#pragma unroll
        for (int r = 0; r < 2; ++r) {               // stage B: 512 chunks of 16B
            int ch = (r << 8) + tid;
            const unsigned short* gb = wsB + (((size_t)((k0 >> 3) + (ch >> 7)) * N_ + n0 + (ch & 127)) << 3);
            load_lds16(gb, (char*)Bs + (r << 12) + (wid << 10));
        }
        __syncthreads();

        short8v a[4], bb[4];
#pragma unroll
        for (int mi = 0; mi < 4; ++mi)
            a[mi] = *(const short8v*)(As + ((wy << 6) + (mi << 4) + lr) * 32 + (q << 3));
#pragma unroll
        for (int ni = 0; ni < 4; ++ni)
            bb[ni] = *(const short8v*)(Bs + (((q << 7) + (wx << 6) + (ni << 4) + lr) << 3));
#pragma unroll
        for (int mi = 0; mi < 4; ++mi)
#pragma unroll
            for (int ni = 0; ni < 4; ++ni)
                acc[mi][ni] = __builtin_amdgcn_mfma_f32_16x16x32_bf16(a[mi], bb[ni], acc[mi][ni], 0, 0, 0);
        __syncthreads();
    }

    // epilogue: D row = out-channel (A side), col = spatial n (B side)
#pragma unroll
    for (int mi = 0; mi < 4; ++mi) {
        int rowb = m0 + (wy << 6) + (mi << 4) + (q << 2);
#pragma unroll
        for (int ni = 0; ni < 4; ++ni) {
            int col = n0 + (wx << 6) + (ni << 4) + lr;
            int b   = col >> 14, p = col & 16383;
#pragma unroll
            for (int r = 0; r < 4; ++r) {
                int row = rowb + r;
                out[((size_t)((b << 8) + row) << 14) + p] = acc[mi][ni][r] + bias[row];
            }
        }
    }
}

extern "C" void kernel_launch(void* const* d_in, const int* in_sizes, int n_in,
                              void* d_out, int out_size, void* d_ws, size_t ws_size,
                              hipStream_t stream) {
    const float* x  = (const float*)d_in[0];
    const float* cw = (const float*)d_in[1];
    const float* cb = (const float*)d_in[2];
    float* out = (float*)d_out;

    unsigned short* wsA = (unsigned short*)d_ws;
    unsigned short* wsB = wsA + 327680;            // 655,360 B offset, 16B aligned

    repack_w<<<320, 256, 0, stream>>>(cw, wsA);
    scan_h<<<256, 256, 0, stream>>>(x, wsB);
    scan_w<<<128, 256, 0, stream>>>(x, wsB);
    gemm_k<<<dim3(1024, 2), 256, 0, stream>>>(wsA, wsB, cb, out);
}

// Round 2
// 550.732 us; speedup vs baseline: 1.3496x; 1.3496x over previous
//
#include <hip/hip_runtime.h>
#include <stdint.h>

// B=8, C=256, H=128, W=128. out = W[256,1280] @ concat(x,cummaxH,revcummaxH,cummaxW,revcummaxW) + bias
// GEMM: M=256, K=1280, N=131072 bf16 MFMA.
// ws: wsA [256][1280] bf16 weights; wsB [kb=160][n=131072][j=8] bf16 (k = kb*8+j).

#define N_  131072
#define K_  1280

typedef unsigned short ushort8v __attribute__((ext_vector_type(8)));
typedef unsigned short ushort4v __attribute__((ext_vector_type(4)));
typedef short          short8v  __attribute__((ext_vector_type(8)));
typedef float          float4v  __attribute__((ext_vector_type(4)));

__device__ __forceinline__ unsigned short f2bf(float f) {
    unsigned int u = __builtin_bit_cast(unsigned int, f);
    u += 0x7fffu + ((u >> 16) & 1u);           // RNE
    return (unsigned short)(u >> 16);
}

__device__ __forceinline__ void load_lds16(const void* g, void* l) {
    __builtin_amdgcn_global_load_lds(
        (const __attribute__((address_space(1))) uint32_t*)g,
        (__attribute__((address_space(3))) uint32_t*)l,
        16, 0, 0);
}

// ---- weights fp32 -> bf16, [M][K] k-contiguous ----
__global__ void repack_w(const float* __restrict__ w, unsigned short* __restrict__ wsA) {
    int idx = blockIdx.x * 256 + threadIdx.x;
    float4 v = ((const float4*)w)[idx];
    ushort4v o = { f2bf(v.x), f2bf(v.y), f2bf(v.z), f2bf(v.w) };
    *(ushort4v*)(wsA + (size_t)idx * 4) = o;
}

// ---- v0 (x), v1 (prefix max over h), v2 (suffix max over h) ----
// grid 1024 = (b:8, cb:32, wq:4); block 256 = (j:8 major, wi:32).
// Thread scans column (b, cb*8+j, :, wq*32+wi). LDS repack -> ushort8 [n][j] stores.
__global__ __launch_bounds__(256) void scan_h(const float* __restrict__ x,
                                              unsigned short* __restrict__ wsB) {
    int idx = blockIdx.x;
    int wq = idx & 3, cb = (idx >> 2) & 31, b = idx >> 7;
    int t = threadIdx.x;
    int j = t >> 5, wi = t & 31;
    const float* src = x + (((size_t)(b * 256 + cb * 8 + j)) << 14) + wq * 32 + wi;
    unsigned short* d0 = wsB + (((size_t)(cb)      * N_) << 3);
    unsigned short* d1 = wsB + (((size_t)(32 + cb) * N_) << 3);
    unsigned short* d2 = wsB + (((size_t)(64 + cb) * N_) << 3);
    size_t nbase = ((size_t)b << 14) + wq * 32;

    __shared__ unsigned short sm0[16 * 32 * 8];   // [hh][wi][j], 8 KB
    __shared__ unsigned short sm1[16 * 32 * 8];

    float r = -INFINITY;
    for (int hb = 0; hb < 8; ++hb) {
        int h0 = hb << 4;
#pragma unroll
        for (int hh = 0; hh < 16; ++hh) {
            float v = src[(size_t)(h0 + hh) << 7];
            r = fmaxf(r, v);
            sm0[((hh << 5) + wi) * 8 + j] = f2bf(v);
            sm1[((hh << 5) + wi) * 8 + j] = f2bf(r);
        }
        __syncthreads();
#pragma unroll
        for (int k = 0; k < 2; ++k) {
            int p = t + (k << 8);
            int hh = p >> 5, wo = p & 31;
            size_t n = nbase + (size_t)(h0 + hh) * 128 + wo;
            ushort8v a = *(const ushort8v*)(sm0 + (((hh << 5) + wo) << 3));
            ushort8v c = *(const ushort8v*)(sm1 + (((hh << 5) + wo) << 3));
            *(ushort8v*)(d0 + (n << 3)) = a;
            *(ushort8v*)(d1 + (n << 3)) = c;
        }
        __syncthreads();
    }
    // suffix pass (reads x again; block footprint is L3-resident)
    r = -INFINITY;
    for (int hb = 7; hb >= 0; --hb) {
        int h0 = hb << 4;
#pragma unroll
        for (int hh = 15; hh >= 0; --hh) {
            float v = src[(size_t)(h0 + hh) << 7];
            r = fmaxf(r, v);
            sm0[((hh << 5) + wi) * 8 + j] = f2bf(r);
        }
        __syncthreads();
#pragma unroll
        for (int k = 0; k < 2; ++k) {
            int p = t + (k << 8);
            int hh = p >> 5, wo = p & 31;
            size_t n = nbase + (size_t)(h0 + hh) * 128 + wo;
            *(ushort8v*)(d2 + (n << 3)) = *(const ushort8v*)(sm0 + (((hh << 5) + wo) << 3));
        }
        __syncthreads();
    }
}

// ---- v3 (prefix max over w), v4 (suffix max over w) ----
// grid 1024 = (b:8, cb:32, hq:4); block 256: scan mapping j=t>>5 (0..7), hh=t&31.
// Thread scans row (b, cb*8+j, hq*32+hh, :) serially; reads staged via LDS transpose.
__global__ __launch_bounds__(256) void scan_w(const float* __restrict__ x,
                                              unsigned short* __restrict__ wsB) {
    int idx = blockIdx.x;
    int hq = idx & 3, cb = (idx >> 2) & 31, b = idx >> 7;
    int t = threadIdx.x;
    int j = t >> 5, hh = t & 31;
    (void)j; (void)hh;

    __shared__ float xs[16][260];                 // [w][row], row = c8*32+hr, pad 260
    __shared__ unsigned short po[32][136];        // [hh][w*8+j], row-pad 136

    const float* xb = x + (((size_t)(b * 256 + cb * 8)) << 14) + ((size_t)(hq * 32) << 7);
    unsigned short* d3 = wsB + (((size_t)(96  + cb) * N_) << 3);
    unsigned short* d4 = wsB + (((size_t)(128 + cb) * N_) << 3);
    size_t nrow0 = ((size_t)b << 14) + (size_t)(hq * 32) * 128;

    // forward sweep: prefix -> d3
    {
        float r = -INFINITY;
        for (int wc = 0; wc < 8; ++wc) {
#pragma unroll
            for (int k = 0; k < 4; ++k) {
                int f = t + (k << 8);
                int row = f >> 2, pos = f & 3;
                float4 v = *(const float4*)(xb + ((size_t)(row >> 5) << 14) +
                                            ((row & 31) << 7) + (wc << 4) + (pos << 2));
                xs[pos * 4 + 0][row] = v.x; xs[pos * 4 + 1][row] = v.y;
                xs[pos * 4 + 2][row] = v.z; xs[pos * 4 + 3][row] = v.w;
            }
            __syncthreads();
#pragma unroll
            for (int w = 0; w < 16; ++w) {
                r = fmaxf(r, xs[w][t]);
                po[t & 31][w * 8 + (t >> 5)] = f2bf(r);
            }
            __syncthreads();
#pragma unroll
            for (int k = 0; k < 2; ++k) {
                int p = t + (k << 8);
                int ph = p >> 4, pw = p & 15;
                size_t n = nrow0 + (size_t)ph * 128 + (wc << 4) + pw;
                *(ushort8v*)(d3 + (n << 3)) = *(const ushort8v*)(&po[ph][pw << 3]);
            }
            __syncthreads();
        }
    }
    // backward sweep: suffix -> d4
    {
        float r = -INFINITY;
        for (int wc = 7; wc >= 0; --wc) {
#pragma unroll
            for (int k = 0; k < 4; ++k) {
                int f = t + (k << 8);
                int row = f >> 2, pos = f & 3;
                float4 v = *(const float4*)(xb + ((size_t)(row >> 5) << 14) +
                                            ((row & 31) << 7) + (wc << 4) + (pos << 2));
                xs[pos * 4 + 0][row] = v.x; xs[pos * 4 + 1][row] = v.y;
                xs[pos * 4 + 2][row] = v.z; xs[pos * 4 + 3][row] = v.w;
            }
            __syncthreads();
#pragma unroll
            for (int w = 15; w >= 0; --w) {
                r = fmaxf(r, xs[w][t]);
                po[t & 31][w * 8 + (t >> 5)] = f2bf(r);
            }
            __syncthreads();
#pragma unroll
            for (int k = 0; k < 2; ++k) {
                int p = t + (k << 8);
                int ph = p >> 4, pw = p & 15;
                size_t n = nrow0 + (size_t)ph * 128 + (wc << 4) + pw;
                *(ushort8v*)(d4 + (n << 3)) = *(const ushort8v*)(&po[ph][pw << 3]);
            }
            __syncthreads();
        }
    }
}

// ---- GEMM: C[256,131072] = A[256,1280] * B[1280,131072], bf16 MFMA ----
__global__ __launch_bounds__(256) void gemm_k(
    const unsigned short* __restrict__ wsA, const unsigned short* __restrict__ wsB,
    const float* __restrict__ bias, float* __restrict__ out) {
    __shared__ __align__(16) unsigned short As[128 * 32];
    __shared__ __align__(16) unsigned short Bs[4 * 128 * 8];

    int tid  = threadIdx.x;
    int lane = tid & 63, wid = tid >> 6;
    int m0 = blockIdx.y << 7;
    int n0 = blockIdx.x << 7;
    int wy = wid >> 1, wx = wid & 1;
    int q  = lane >> 4, lr = lane & 15;

    float4v acc[4][4];
#pragma unroll
    for (int mi = 0; mi < 4; ++mi)
#pragma unroll
        for (int ni = 0; ni < 4; ++ni)
            acc[mi][ni] = (float4v){0.f, 0.f, 0.f, 0.f};

    for (int kt = 0; kt < 40; ++kt) {
        int k0 = kt << 5;
#pragma unroll
        for (int r = 0; r < 2; ++r) {
            int ch = (r << 8) + tid;
            const unsigned short* ga = wsA + (size_t)(m0 + (ch >> 2)) * K_ + k0 + ((ch & 3) << 3);
            load_lds16(ga, (char*)As + (r << 12) + (wid << 10));
        }
#pragma unroll
        for (int r = 0; r < 2; ++r) {
            int ch = (r << 8) + tid;
            const unsigned short* gb = wsB + (((size_t)((k0 >> 3) + (ch >> 7)) * N_ + n0 + (ch & 127)) << 3);
            load_lds16(gb, (char*)Bs + (r << 12) + (wid << 10));
        }
        __syncthreads();

        short8v a[4], bb[4];
#pragma unroll
        for (int mi = 0; mi < 4; ++mi)
            a[mi] = *(const short8v*)(As + ((wy << 6) + (mi << 4) + lr) * 32 + (q << 3));
#pragma unroll
        for (int ni = 0; ni < 4; ++ni)
            bb[ni] = *(const short8v*)(Bs + (((q << 7) + (wx << 6) + (ni << 4) + lr) << 3));
#pragma unroll
        for (int mi = 0; mi < 4; ++mi)
#pragma unroll
            for (int ni = 0; ni < 4; ++ni)
                acc[mi][ni] = __builtin_amdgcn_mfma_f32_16x16x32_bf16(a[mi], bb[ni], acc[mi][ni], 0, 0, 0);
        __syncthreads();
    }

#pragma unroll
    for (int mi = 0; mi < 4; ++mi) {
        int rowb = m0 + (wy << 6) + (mi << 4) + (q << 2);
#pragma unroll
        for (int ni = 0; ni < 4; ++ni) {
            int col = n0 + (wx << 6) + (ni << 4) + lr;
            int b   = col >> 14, p = col & 16383;
#pragma unroll
            for (int r = 0; r < 4; ++r) {
                int row = rowb + r;
                out[((size_t)((b << 8) + row) << 14) + p] = acc[mi][ni][r] + bias[row];
            }
        }
    }
}

extern "C" void kernel_launch(void* const* d_in, const int* in_sizes, int n_in,
                              void* d_out, int out_size, void* d_ws, size_t ws_size,
                              hipStream_t stream) {
    const float* x  = (const float*)d_in[0];
    const float* cw = (const float*)d_in[1];
    const float* cb = (const float*)d_in[2];
    float* out = (float*)d_out;

    unsigned short* wsA = (unsigned short*)d_ws;
    unsigned short* wsB = wsA + 327680;

    repack_w<<<320, 256, 0, stream>>>(cw, wsA);
    scan_h<<<1024, 256, 0, stream>>>(x, wsB);
    scan_w<<<1024, 256, 0, stream>>>(x, wsB);
    gemm_k<<<dim3(1024, 2), 256, 0, stream>>>(wsA, wsB, cb, out);
}